// Round 8
// baseline (5743.373 us; speedup 1.0000x reference)
//
#include <hip/hip_runtime.h>
#include <math.h>

#define SS 512
#define BB 64
#define II 512
#define HH 512
#define MM (SS*BB)

typedef _Float16 h2 __attribute__((ext_vector_type(2)));
typedef _Float16 f16x8 __attribute__((ext_vector_type(8)));
typedef float f32x4 __attribute__((ext_vector_type(4)));

__device__ __forceinline__ h2 bc_h2(unsigned u) { return __builtin_bit_cast(h2, u); }
__device__ __forceinline__ unsigned bc_u(h2 v) { return __builtin_bit_cast(unsigned, v); }
__device__ __forceinline__ h2 pk(float x, float y) {
    return __builtin_bit_cast(h2, __builtin_amdgcn_cvt_pkrtz(x, y));
}

#if __has_builtin(__builtin_amdgcn_exp2f)
#define EXP2F __builtin_amdgcn_exp2f
#else
#define EXP2F exp2f
#endif
#if __has_builtin(__builtin_amdgcn_rcpf)
#define RCPF __builtin_amdgcn_rcpf
#else
#define RCPF(x) (1.0f / (x))
#endif

// branch-free tanh: tanh(z) = 1 - 2/(e^{2z}+1); exact at +-inf.
__device__ __forceinline__ float fast_tanh(float z) {
    float e = EXP2F(z * 2.885390081777927f);
    return 1.0f - 2.0f * RCPF(e + 1.0f);
}

// ---------------------------------------------------------------------------
// Input projection via f16 MFMA (unchanged from round 7, ~30-38 us).
// ---------------------------------------------------------------------------
__global__ __launch_bounds__(256) void k_ingemm2(const float* __restrict__ X,
                                                 const float* __restrict__ W1,
                                                 const float* __restrict__ b1,
                                                 float* __restrict__ C) {
    __shared__ __align__(16) _Float16 As[128 * 32];
    __shared__ __align__(16) _Float16 Bs[128 * 32];
    const int bm = blockIdx.x * 128;
    const int bn = blockIdx.y * 128;
    const int t = threadIdx.x;
    const int lane = t & 63;
    const int w = t >> 6;
    const int srow = t >> 1;
    const int kb0 = (t & 1) * 32;
    const int wm = (w >> 1) * 64, wn = (w & 1) * 64;

    f32x4 acc[4][4];
#pragma unroll
    for (int i = 0; i < 4; i++)
#pragma unroll
        for (int j = 0; j < 4; j++) acc[i][j] = f32x4{0.f, 0.f, 0.f, 0.f};

    const float* xs = X + (size_t)(bm + srow) * II + (t & 1) * 16;
    const float* ws = W1 + (size_t)(bn + srow) * II + (t & 1) * 16;
    char* asb = (char*)As + srow * 64;
    char* bsb = (char*)Bs + srow * 64;
    const int sw = (srow & 3) << 4;

    const int frow = lane & 15;
    const int fkb = (lane >> 4) * 16;
    const int fsw = (frow & 3) << 4;

    for (int kt = 0; kt < 16; ++kt) {
        float4 a0 = *(const float4*)(xs + kt * 32 + 0);
        float4 a1 = *(const float4*)(xs + kt * 32 + 4);
        float4 a2 = *(const float4*)(xs + kt * 32 + 8);
        float4 a3 = *(const float4*)(xs + kt * 32 + 12);
        float4 c0 = *(const float4*)(ws + kt * 32 + 0);
        float4 c1 = *(const float4*)(ws + kt * 32 + 4);
        float4 c2 = *(const float4*)(ws + kt * 32 + 8);
        float4 c3 = *(const float4*)(ws + kt * 32 + 12);
        __syncthreads();
        uint4 u0, u1, v0, v1;
        u0.x = bc_u(pk(a0.x, a0.y)); u0.y = bc_u(pk(a0.z, a0.w));
        u0.z = bc_u(pk(a1.x, a1.y)); u0.w = bc_u(pk(a1.z, a1.w));
        u1.x = bc_u(pk(a2.x, a2.y)); u1.y = bc_u(pk(a2.z, a2.w));
        u1.z = bc_u(pk(a3.x, a3.y)); u1.w = bc_u(pk(a3.z, a3.w));
        v0.x = bc_u(pk(c0.x, c0.y)); v0.y = bc_u(pk(c0.z, c0.w));
        v0.z = bc_u(pk(c1.x, c1.y)); v0.w = bc_u(pk(c1.z, c1.w));
        v1.x = bc_u(pk(c2.x, c2.y)); v1.y = bc_u(pk(c2.z, c2.w));
        v1.z = bc_u(pk(c3.x, c3.y)); v1.w = bc_u(pk(c3.z, c3.w));
        *(uint4*)(asb + ((kb0 + 0) ^ sw)) = u0;
        *(uint4*)(asb + ((kb0 + 16) ^ sw)) = u1;
        *(uint4*)(bsb + ((kb0 + 0) ^ sw)) = v0;
        *(uint4*)(bsb + ((kb0 + 16) ^ sw)) = v1;
        __syncthreads();

        f16x8 af[4], bf[4];
#pragma unroll
        for (int i = 0; i < 4; i++) {
            const int ar = wm + 16 * i + frow;
            af[i] = *(const f16x8*)((const char*)As + ar * 64 + (fkb ^ fsw));
            const int br = wn + 16 * i + frow;
            bf[i] = *(const f16x8*)((const char*)Bs + br * 64 + (fkb ^ fsw));
        }
#pragma unroll
        for (int i = 0; i < 4; i++)
#pragma unroll
            for (int j = 0; j < 4; j++)
                acc[i][j] = __builtin_amdgcn_mfma_f32_16x16x32_f16(
                    af[i], bf[j], acc[i][j], 0, 0, 0);
    }

    const int erow = bm + wm + (lane >> 4) * 4;
    const int ecol = bn + wn + (lane & 15);
#pragma unroll
    for (int j = 0; j < 4; j++) {
        const float bj = b1[ecol + 16 * j];
#pragma unroll
        for (int i = 0; i < 4; i++)
#pragma unroll
            for (int r = 0; r < 4; r++)
                C[(size_t)(erow + 16 * i + r) * HH + ecol + 16 * j] =
                    acc[i][j][r] + bj;
    }
}

// ---------------------------------------------------------------------------
// Recurrence split 2 WGs per batch element (128 WGs x 512 thr, 1 WG/CU):
//   WG (b = wgid&63, half = wgid>>6) owns cols [half*256, half*256+256).
//   Weights ALL in registers: thread = (lane, wave wv): 4 cols (lane+64ci),
//   32 k-pairs = 16 own-half + 16 partner-half -> wreg[4][32] = 128 VGPRs.
//   Per step: phase1 MACs vs OWN h-half (LDS, available at once) overlap the
//   partner's flag+data latency; then spin (lane0/wave), acquire fence,
//   read partner h-pairs straight from global (L1-bypassed), phase2 MACs.
//   Partials part[8][256] in LDS; waves 0-3 combine + tanh + publish:
//   out (f32), own-LDS h (f16), global hbuf (f16 pairs, double-buffered by
//   step parity -> rigorous overwrite ordering), then one release-atomicAdd.
//   Flags/hbuf zeroed per launch by hipMemsetAsync (replay-deterministic).
//   Deadlock-free: 128 WGs <= 256 CUs -> all co-resident.
// ---------------------------------------------------------------------------
__global__ __attribute__((amdgpu_flat_work_group_size(512, 512)))
__attribute__((amdgpu_waves_per_eu(2, 2)))
void k_rec7(const float* __restrict__ W2,
            const float* __restrict__ b2,
            float* __restrict__ out,
            float* __restrict__ hlast,
            unsigned* __restrict__ arr,    // [64] arrival counters
            unsigned* __restrict__ hbuf) { // [2][64][256] u32 h-pairs
    const int wgid = blockIdx.x;
    const int b = wgid & 63;
    const int half = wgid >> 6;
    const int t = threadIdx.x;
    const int lane = t & 63;
    const int wv = t >> 6;                // wave = k-subchunk
    const int colbase = half << 8;

    __shared__ float part[8][256];
    __shared__ __align__(4) _Float16 hsmem[256];   // OWN half of h
    const unsigned* hs32 = (const unsigned*)hsmem;

    // one-time: pack this thread's W2 slice into 128 h2 registers.
    h2 wreg[4][32];
    {
        const int pown = (half << 7) + (wv << 4);        // own-half pair base
        const int popp = ((1 - half) << 7) + (wv << 4);  // partner pair base
#pragma unroll
        for (int ci = 0; ci < 4; ci++) {
            const float2* wrow =
                (const float2*)(W2 + (size_t)(colbase + lane + (ci << 6)) * HH);
#pragma unroll
            for (int g = 0; g < 16; g++) {
                float2 f = wrow[pown + g];
                wreg[ci][g] = pk(f.x, f.y);
            }
#pragma unroll
            for (int g = 0; g < 16; g++) {
                float2 f = wrow[popp + g];
                wreg[ci][16 + g] = pk(f.x, f.y);
            }
        }
    }
    if (t < 256) hsmem[t] = (_Float16)0.0f;
    float bias = 0.f;
    if (t < 256) bias = b2[colbase + t];
    float* pout = out + (size_t)b * HH + colbase + t;   // valid use t<256
    const int rdIdx = b * 256 + ((1 - half) << 7) + (wv << 4) + (lane & 15);
    const int wrIdx = b * 256 + (half << 7) + (t >> 1);
    float hn = 0.0f;
    __syncthreads();

    for (int s = 0; s < SS; ++s) {
        float xpv = 0.f;
        if (t < 256) xpv = *pout;          // early; hidden under MACs

        // ---- phase 1: own-half h(s-1) from LDS ----
        unsigned hv1 = hs32[(wv << 4) + (lane & 15)];
        h2 aA[4], aB[4];
#pragma unroll
        for (int ci = 0; ci < 4; ci++) { aA[ci] = h2{0, 0}; aB[ci] = h2{0, 0}; }
#pragma unroll
        for (int g = 0; g < 16; g++) {
            h2 hp = bc_h2((unsigned)__builtin_amdgcn_readlane((int)hv1, g));
            if (g & 1) {
                aB[0] += wreg[0][g] * hp; aB[1] += wreg[1][g] * hp;
                aB[2] += wreg[2][g] * hp; aB[3] += wreg[3][g] * hp;
            } else {
                aA[0] += wreg[0][g] * hp; aA[1] += wreg[1][g] * hp;
                aA[2] += wreg[2][g] * hp; aA[3] += wreg[3][g] * hp;
            }
        }

        // ---- wait for partner's h(s-1), read it from global ----
        if (s > 0) {
            if (lane == 0) {
                while (__hip_atomic_load(&arr[b], __ATOMIC_RELAXED,
                                         __HIP_MEMORY_SCOPE_AGENT) <
                       2u * (unsigned)s) {}
            }
            __builtin_amdgcn_fence(__ATOMIC_ACQUIRE, "agent");
        }
        unsigned hv2 = __hip_atomic_load(
            &hbuf[(((unsigned)s & 1u) ^ 1u) * 16384 + rdIdx],
            __ATOMIC_RELAXED, __HIP_MEMORY_SCOPE_AGENT);

        // ---- phase 2: partner-half MACs ----
#pragma unroll
        for (int g = 0; g < 16; g++) {
            h2 hp = bc_h2((unsigned)__builtin_amdgcn_readlane((int)hv2, g));
            if (g & 1) {
                aB[0] += wreg[0][16 + g] * hp; aB[1] += wreg[1][16 + g] * hp;
                aB[2] += wreg[2][16 + g] * hp; aB[3] += wreg[3][16 + g] * hp;
            } else {
                aA[0] += wreg[0][16 + g] * hp; aA[1] += wreg[1][16 + g] * hp;
                aA[2] += wreg[2][16 + g] * hp; aA[3] += wreg[3][16 + g] * hp;
            }
        }
#pragma unroll
        for (int ci = 0; ci < 4; ci++) {
            h2 sv = aA[ci] + aB[ci];
            part[wv][lane + (ci << 6)] = (float)sv.x + (float)sv.y;
        }
        __syncthreads();  // A: partials visible

        if (t < 256) {
            float z = part[0][t] + part[1][t] + part[2][t] + part[3][t] +
                      part[4][t] + part[5][t] + part[6][t] + part[7][t] +
                      bias + xpv;
            hn = fast_tanh(z);
            *pout = hn;
            hsmem[t] = (_Float16)hn;
            float ho = __shfl_xor(hn, 1);
            if (!(t & 1)) {
                __hip_atomic_store(
                    &hbuf[((unsigned)s & 1u) * 16384 + wrIdx],
                    bc_u(pk(hn, ho)),
                    __ATOMIC_RELAXED, __HIP_MEMORY_SCOPE_AGENT);
            }
        }
        pout += BB * HH;
        __syncthreads();  // B: hsmem + global stores drained (vmcnt0@barrier)
        if (t == 0)
            __hip_atomic_fetch_add(&arr[b], 1u, __ATOMIC_RELEASE,
                                   __HIP_MEMORY_SCOPE_AGENT);
    }
    if (t < 256) hlast[(size_t)b * HH + colbase + t] = hn;
}

extern "C" void kernel_launch(void* const* d_in, const int* in_sizes, int n_in,
                              void* d_out, int out_size, void* d_ws, size_t ws_size,
                              hipStream_t stream) {
    const float* x  = (const float*)d_in[0];
    const float* W1 = (const float*)d_in[1];
    const float* b1 = (const float*)d_in[2];
    const float* W2 = (const float*)d_in[3];
    const float* b2 = (const float*)d_in[4];
    float* out = (float*)d_out;

    unsigned* hbuf = (unsigned*)d_ws;                         // 128 KB
    unsigned* arr  = (unsigned*)((char*)d_ws + 128 * 1024);   // 256 B

    // Reset exchange flags/buffer every launch (graph-replay determinism).
    hipMemsetAsync(d_ws, 0, 128 * 1024 + 256, stream);
    k_ingemm2<<<dim3(MM / 128, HH / 128), 256, 0, stream>>>(x, W1, b1, out);
    k_rec7<<<128, 512, 0, stream>>>(W2, b2, out, out + (size_t)SS * BB * HH,
                                    arr, hbuf);
}

// Round 9
// 875.760 us; speedup vs baseline: 6.5582x; 6.5582x over previous
//
#include <hip/hip_runtime.h>
#include <math.h>

#define SS 512
#define BB 64
#define II 512
#define HH 512
#define MM (SS*BB)

typedef _Float16 h2 __attribute__((ext_vector_type(2)));
typedef _Float16 f16x8 __attribute__((ext_vector_type(8)));
typedef float f32x4 __attribute__((ext_vector_type(4)));

__device__ __forceinline__ h2 bc_h2(unsigned u) { return __builtin_bit_cast(h2, u); }
__device__ __forceinline__ unsigned bc_u(h2 v) { return __builtin_bit_cast(unsigned, v); }
__device__ __forceinline__ h2 pk(float x, float y) {
    return __builtin_bit_cast(h2, __builtin_amdgcn_cvt_pkrtz(x, y));
}

#if __has_builtin(__builtin_amdgcn_exp2f)
#define EXP2F __builtin_amdgcn_exp2f
#else
#define EXP2F exp2f
#endif
#if __has_builtin(__builtin_amdgcn_rcpf)
#define RCPF __builtin_amdgcn_rcpf
#else
#define RCPF(x) (1.0f / (x))
#endif

// branch-free tanh: tanh(z) = 1 - 2/(e^{2z}+1); exact at +-inf.
__device__ __forceinline__ float fast_tanh(float z) {
    float e = EXP2F(z * 2.885390081777927f);
    return 1.0f - 2.0f * RCPF(e + 1.0f);
}

// Raw workgroup barrier that drains ONLY LDS (lgkmcnt), letting global
// stores/loads float across it. __syncthreads would add s_waitcnt vmcnt(0),
// putting the ~900-cyc HBM out-store latency on the per-step critical path.
__device__ __forceinline__ void bar_lds() {
    asm volatile("s_waitcnt lgkmcnt(0)\n\ts_barrier" ::: "memory");
}

// ---------------------------------------------------------------------------
// Input projection via f16 MFMA (unchanged from round 7, ~38 us).
// ---------------------------------------------------------------------------
__global__ __launch_bounds__(256) void k_ingemm2(const float* __restrict__ X,
                                                 const float* __restrict__ W1,
                                                 const float* __restrict__ b1,
                                                 float* __restrict__ C) {
    __shared__ __align__(16) _Float16 As[128 * 32];
    __shared__ __align__(16) _Float16 Bs[128 * 32];
    const int bm = blockIdx.x * 128;
    const int bn = blockIdx.y * 128;
    const int t = threadIdx.x;
    const int lane = t & 63;
    const int w = t >> 6;
    const int srow = t >> 1;
    const int kb0 = (t & 1) * 32;
    const int wm = (w >> 1) * 64, wn = (w & 1) * 64;

    f32x4 acc[4][4];
#pragma unroll
    for (int i = 0; i < 4; i++)
#pragma unroll
        for (int j = 0; j < 4; j++) acc[i][j] = f32x4{0.f, 0.f, 0.f, 0.f};

    const float* xs = X + (size_t)(bm + srow) * II + (t & 1) * 16;
    const float* ws = W1 + (size_t)(bn + srow) * II + (t & 1) * 16;
    char* asb = (char*)As + srow * 64;
    char* bsb = (char*)Bs + srow * 64;
    const int sw = (srow & 3) << 4;

    const int frow = lane & 15;
    const int fkb = (lane >> 4) * 16;
    const int fsw = (frow & 3) << 4;

    for (int kt = 0; kt < 16; ++kt) {
        float4 a0 = *(const float4*)(xs + kt * 32 + 0);
        float4 a1 = *(const float4*)(xs + kt * 32 + 4);
        float4 a2 = *(const float4*)(xs + kt * 32 + 8);
        float4 a3 = *(const float4*)(xs + kt * 32 + 12);
        float4 c0 = *(const float4*)(ws + kt * 32 + 0);
        float4 c1 = *(const float4*)(ws + kt * 32 + 4);
        float4 c2 = *(const float4*)(ws + kt * 32 + 8);
        float4 c3 = *(const float4*)(ws + kt * 32 + 12);
        __syncthreads();
        uint4 u0, u1, v0, v1;
        u0.x = bc_u(pk(a0.x, a0.y)); u0.y = bc_u(pk(a0.z, a0.w));
        u0.z = bc_u(pk(a1.x, a1.y)); u0.w = bc_u(pk(a1.z, a1.w));
        u1.x = bc_u(pk(a2.x, a2.y)); u1.y = bc_u(pk(a2.z, a2.w));
        u1.z = bc_u(pk(a3.x, a3.y)); u1.w = bc_u(pk(a3.z, a3.w));
        v0.x = bc_u(pk(c0.x, c0.y)); v0.y = bc_u(pk(c0.z, c0.w));
        v0.z = bc_u(pk(c1.x, c1.y)); v0.w = bc_u(pk(c1.z, c1.w));
        v1.x = bc_u(pk(c2.x, c2.y)); v1.y = bc_u(pk(c2.z, c2.w));
        v1.z = bc_u(pk(c3.x, c3.y)); v1.w = bc_u(pk(c3.z, c3.w));
        *(uint4*)(asb + ((kb0 + 0) ^ sw)) = u0;
        *(uint4*)(asb + ((kb0 + 16) ^ sw)) = u1;
        *(uint4*)(bsb + ((kb0 + 0) ^ sw)) = v0;
        *(uint4*)(bsb + ((kb0 + 16) ^ sw)) = v1;
        __syncthreads();

        f16x8 af[4], bf[4];
#pragma unroll
        for (int i = 0; i < 4; i++) {
            const int ar = wm + 16 * i + frow;
            af[i] = *(const f16x8*)((const char*)As + ar * 64 + (fkb ^ fsw));
            const int br = wn + 16 * i + frow;
            bf[i] = *(const f16x8*)((const char*)Bs + br * 64 + (fkb ^ fsw));
        }
#pragma unroll
        for (int i = 0; i < 4; i++)
#pragma unroll
            for (int j = 0; j < 4; j++)
                acc[i][j] = __builtin_amdgcn_mfma_f32_16x16x32_f16(
                    af[i], bf[j], acc[i][j], 0, 0, 0);
    }

    const int erow = bm + wm + (lane >> 4) * 4;
    const int ecol = bn + wn + (lane & 15);
#pragma unroll
    for (int j = 0; j < 4; j++) {
        const float bj = b1[ecol + 16 * j];
#pragma unroll
        for (int i = 0; i < 4; i++)
#pragma unroll
            for (int r = 0; r < 4; r++)
                C[(size_t)(erow + 16 * i + r) * HH + ecol + 16 * j] =
                    acc[i][j][r] + bj;
    }
}

// ---------------------------------------------------------------------------
// Recurrence (round-7 k_rec6 structure + raw LDS-only barriers):
//   64 WGs x 512 thr (1 WG/CU). Wave w = k-chunk (pairs [32w,32w+32));
//   lane L owns cols L+64*ci, ci=0..7. ci 0..5 weights in regs (192 h2),
//   ci 6,7 in 128KB LDS. h: 1 ds_read_b32 + 32 readlanes per step.
//   MAC: v_pk_fma_f16, A/B dual chains. part[8][512] f32 combine.
//   bar_lds() instead of __syncthreads: only lgkmcnt(0) drains; the per-step
//   out-store (HBM, ~900cyc) and xp load float across barriers. The xp
//   load's own vmcnt wait is inserted at its use (hidden under MACs).
// ---------------------------------------------------------------------------
__global__ __attribute__((amdgpu_flat_work_group_size(512, 512)))
__attribute__((amdgpu_waves_per_eu(2, 2)))
void k_rec8(const float* __restrict__ W2,
            const float* __restrict__ b2,
            float* __restrict__ out,
            float* __restrict__ hlast) {
    const int b = blockIdx.x;
    const int t = threadIdx.x;
    const int lane = t & 63;
    const int w = t >> 6;   // k-chunk = wave index (wave-uniform)

    __shared__ uint4 wlds[16][512];                  // 128 KB: cols ci=6,7
    __shared__ float part[8][512];                   // 16 KB partials
    __shared__ __align__(4) _Float16 hsmem[HH];      // 1 KB
    const unsigned* hs32 = (const unsigned*)hsmem;

    // one-time: pack W2 slices (col c = lane + 64*ci, k pairs [32w,32w+32))
    h2 wreg[6][32];
#pragma unroll
    for (int ci = 0; ci < 6; ci++) {
        const float2* src =
            (const float2*)(W2 + (size_t)(lane + 64 * ci) * HH) + (w << 5);
#pragma unroll
        for (int g = 0; g < 32; g++) wreg[ci][g] = pk(src[g].x, src[g].y);
    }
#pragma unroll
    for (int cc = 0; cc < 2; cc++) {
        const float2* src =
            (const float2*)(W2 + (size_t)(lane + 384 + 64 * cc) * HH) + (w << 5);
#pragma unroll
        for (int q = 0; q < 8; q++) {
            uint4 u;
            u.x = bc_u(pk(src[4 * q + 0].x, src[4 * q + 0].y));
            u.y = bc_u(pk(src[4 * q + 1].x, src[4 * q + 1].y));
            u.z = bc_u(pk(src[4 * q + 2].x, src[4 * q + 2].y));
            u.w = bc_u(pk(src[4 * q + 3].x, src[4 * q + 3].y));
            wlds[cc * 8 + q][t] = u;
        }
    }
    hsmem[t] = (_Float16)0.0f;
    const float bias = b2[t];
    float* po = out + (size_t)b * HH + t;
    float hn = 0.0f;
    __syncthreads();   // init: full barrier once is fine

    for (int step = 0; step < SS; ++step) {
        float xpv = *po;                       // early; used in combine
        unsigned hv = hs32[(w << 5) + (lane & 31)];  // lane L: pair 32w+L

        h2 accA[8], accB[8];
#pragma unroll
        for (int c = 0; c < 8; c++) { accA[c] = h2{0, 0}; accB[c] = h2{0, 0}; }

#pragma unroll
        for (int q = 0; q < 8; q++) {
            uint4 u6 = wlds[q][t];
            uint4 u7 = wlds[8 + q][t];
            unsigned w6[4] = {u6.x, u6.y, u6.z, u6.w};
            unsigned w7[4] = {u7.x, u7.y, u7.z, u7.w};
#pragma unroll
            for (int gg = 0; gg < 4; gg++) {
                const int g = 4 * q + gg;
                h2 hp = bc_h2((unsigned)__builtin_amdgcn_readlane((int)hv, g));
                if (gg & 1) {
                    accB[0] += wreg[0][g] * hp;
                    accB[1] += wreg[1][g] * hp;
                    accB[2] += wreg[2][g] * hp;
                    accB[3] += wreg[3][g] * hp;
                    accB[4] += wreg[4][g] * hp;
                    accB[5] += wreg[5][g] * hp;
                    accB[6] += bc_h2(w6[gg]) * hp;
                    accB[7] += bc_h2(w7[gg]) * hp;
                } else {
                    accA[0] += wreg[0][g] * hp;
                    accA[1] += wreg[1][g] * hp;
                    accA[2] += wreg[2][g] * hp;
                    accA[3] += wreg[3][g] * hp;
                    accA[4] += wreg[4][g] * hp;
                    accA[5] += wreg[5][g] * hp;
                    accA[6] += bc_h2(w6[gg]) * hp;
                    accA[7] += bc_h2(w7[gg]) * hp;
                }
            }
        }
#pragma unroll
        for (int c = 0; c < 8; c++) {
            h2 s = accA[c] + accB[c];
            part[w][lane + 64 * c] = (float)s.x + (float)s.y;  // conflict-free
        }
        bar_lds();  // A: partials visible; h reads drained (lgkm only)

        float z = part[0][t] + part[1][t] + part[2][t] + part[3][t] +
                  part[4][t] + part[5][t] + part[6][t] + part[7][t] +
                  bias + xpv;
        hn = fast_tanh(z);
        hsmem[t] = (_Float16)hn;
        *po = hn;          // floats across barriers; nobody reads it
        po += BB * HH;
        bar_lds();  // B: new h visible; part safe to overwrite
    }
    hlast[(size_t)b * HH + t] = hn;
}

extern "C" void kernel_launch(void* const* d_in, const int* in_sizes, int n_in,
                              void* d_out, int out_size, void* d_ws, size_t ws_size,
                              hipStream_t stream) {
    const float* x  = (const float*)d_in[0];
    const float* W1 = (const float*)d_in[1];
    const float* b1 = (const float*)d_in[2];
    const float* W2 = (const float*)d_in[3];
    const float* b2 = (const float*)d_in[4];
    float* out = (float*)d_out;

    k_ingemm2<<<dim3(MM / 128, HH / 128), 256, 0, stream>>>(x, W1, b1, out);
    k_rec8<<<BB, 512, 0, stream>>>(W2, b2, out, out + (size_t)SS * BB * HH);
}

// Round 10
// 710.668 us; speedup vs baseline: 8.0817x; 1.2323x over previous
//
#include <hip/hip_runtime.h>
#include <math.h>

#define SS 512
#define BB 64
#define II 512
#define HH 512
#define MM (SS*BB)
#define HXC_WORDS ((size_t)SS * BB * 256)          // [s][b][half][128] u32
#define HXC_BYTES (HXC_WORDS * 4)                  // 33,554,432 B

typedef _Float16 h2 __attribute__((ext_vector_type(2)));
typedef _Float16 f16x8 __attribute__((ext_vector_type(8)));
typedef float f32x4 __attribute__((ext_vector_type(4)));

__device__ __forceinline__ h2 bc_h2(unsigned u) { return __builtin_bit_cast(h2, u); }
__device__ __forceinline__ unsigned bc_u(h2 v) { return __builtin_bit_cast(unsigned, v); }
__device__ __forceinline__ h2 pk(float x, float y) {
    return __builtin_bit_cast(h2, __builtin_amdgcn_cvt_pkrtz(x, y));
}

#if __has_builtin(__builtin_amdgcn_exp2f)
#define EXP2F __builtin_amdgcn_exp2f
#else
#define EXP2F exp2f
#endif
#if __has_builtin(__builtin_amdgcn_rcpf)
#define RCPF __builtin_amdgcn_rcpf
#else
#define RCPF(x) (1.0f / (x))
#endif

__device__ __forceinline__ float fast_tanh(float z) {
    float e = EXP2F(z * 2.885390081777927f);
    return 1.0f - 2.0f * RCPF(e + 1.0f);
}

// LDS-only workgroup barrier (no vmcnt drain).
__device__ __forceinline__ void bar_lds() {
    asm volatile("s_waitcnt lgkmcnt(0)\n\ts_barrier" ::: "memory");
}

// ---------------------------------------------------------------------------
// Input projection via f16 MFMA (unchanged, ~38 us).
// ---------------------------------------------------------------------------
__global__ __launch_bounds__(256) void k_ingemm2(const float* __restrict__ X,
                                                 const float* __restrict__ W1,
                                                 const float* __restrict__ b1,
                                                 float* __restrict__ C) {
    __shared__ __align__(16) _Float16 As[128 * 32];
    __shared__ __align__(16) _Float16 Bs[128 * 32];
    const int bm = blockIdx.x * 128;
    const int bn = blockIdx.y * 128;
    const int t = threadIdx.x;
    const int lane = t & 63;
    const int w = t >> 6;
    const int srow = t >> 1;
    const int kb0 = (t & 1) * 32;
    const int wm = (w >> 1) * 64, wn = (w & 1) * 64;

    f32x4 acc[4][4];
#pragma unroll
    for (int i = 0; i < 4; i++)
#pragma unroll
        for (int j = 0; j < 4; j++) acc[i][j] = f32x4{0.f, 0.f, 0.f, 0.f};

    const float* xs = X + (size_t)(bm + srow) * II + (t & 1) * 16;
    const float* ws = W1 + (size_t)(bn + srow) * II + (t & 1) * 16;
    char* asb = (char*)As + srow * 64;
    char* bsb = (char*)Bs + srow * 64;
    const int sw = (srow & 3) << 4;

    const int frow = lane & 15;
    const int fkb = (lane >> 4) * 16;
    const int fsw = (frow & 3) << 4;

    for (int kt = 0; kt < 16; ++kt) {
        float4 a0 = *(const float4*)(xs + kt * 32 + 0);
        float4 a1 = *(const float4*)(xs + kt * 32 + 4);
        float4 a2 = *(const float4*)(xs + kt * 32 + 8);
        float4 a3 = *(const float4*)(xs + kt * 32 + 12);
        float4 c0 = *(const float4*)(ws + kt * 32 + 0);
        float4 c1 = *(const float4*)(ws + kt * 32 + 4);
        float4 c2 = *(const float4*)(ws + kt * 32 + 8);
        float4 c3 = *(const float4*)(ws + kt * 32 + 12);
        __syncthreads();
        uint4 u0, u1, v0, v1;
        u0.x = bc_u(pk(a0.x, a0.y)); u0.y = bc_u(pk(a0.z, a0.w));
        u0.z = bc_u(pk(a1.x, a1.y)); u0.w = bc_u(pk(a1.z, a1.w));
        u1.x = bc_u(pk(a2.x, a2.y)); u1.y = bc_u(pk(a2.z, a2.w));
        u1.z = bc_u(pk(a3.x, a3.y)); u1.w = bc_u(pk(a3.z, a3.w));
        v0.x = bc_u(pk(c0.x, c0.y)); v0.y = bc_u(pk(c0.z, c0.w));
        v0.z = bc_u(pk(c1.x, c1.y)); v0.w = bc_u(pk(c1.z, c1.w));
        v1.x = bc_u(pk(c2.x, c2.y)); v1.y = bc_u(pk(c2.z, c2.w));
        v1.z = bc_u(pk(c3.x, c3.y)); v1.w = bc_u(pk(c3.z, c3.w));
        *(uint4*)(asb + ((kb0 + 0) ^ sw)) = u0;
        *(uint4*)(asb + ((kb0 + 16) ^ sw)) = u1;
        *(uint4*)(bsb + ((kb0 + 0) ^ sw)) = v0;
        *(uint4*)(bsb + ((kb0 + 16) ^ sw)) = v1;
        __syncthreads();

        f16x8 af[4], bf[4];
#pragma unroll
        for (int i = 0; i < 4; i++) {
            const int ar = wm + 16 * i + frow;
            af[i] = *(const f16x8*)((const char*)As + ar * 64 + (fkb ^ fsw));
            const int br = wn + 16 * i + frow;
            bf[i] = *(const f16x8*)((const char*)Bs + br * 64 + (fkb ^ fsw));
        }
#pragma unroll
        for (int i = 0; i < 4; i++)
#pragma unroll
            for (int j = 0; j < 4; j++)
                acc[i][j] = __builtin_amdgcn_mfma_f32_16x16x32_f16(
                    af[i], bf[j], acc[i][j], 0, 0, 0);
    }

    const int erow = bm + wm + (lane >> 4) * 4;
    const int ecol = bn + wn + (lane & 15);
#pragma unroll
    for (int j = 0; j < 4; j++) {
        const float bj = b1[ecol + 16 * j];
#pragma unroll
        for (int i = 0; i < 4; i++)
#pragma unroll
            for (int r = 0; r < 4; r++)
                C[(size_t)(erow + 16 * i + r) * HH + ecol + 16 * j] =
                    acc[i][j][r] + bj;
    }
}

// ---------------------------------------------------------------------------
// Split recurrence: 2 WGs per b (128 WGs x 512 thr, 1 WG/CU enforced by
// waves_per_eu max). WG (b = wgid&63, half = wgid>>6) owns cols
// [256*half, 256*half+256). Partner pair (wgid, wgid^64) are == mod 8 ->
// same XCD under round-robin dispatch (perf only; correctness independent).
//   Weights: FULLY register-resident. Thread (lane L, wave wv): 4 cols
//   (colbase+L+64ci), 32 k-pairs = own pairs [16wv,16wv+16) + partner pairs
//   [16wv,16wv+16) -> wreg[4][32] = 128 VGPRs. No LDS weights (LDS ~9KB).
//   Exchange: flagless write-once slot buffer hxc[s][b][half][128] u32,
//   sentinel 0xFFFFFFFF (f16 NaN pair; tanh never produces it). Producer:
//   one relaxed agent atomic_store per pair. Consumer: spin atomic_load own
//   word until != sentinel (datum IS the sync; no fence/flag/counter, and
//   bar_lds never drains vmcnt, so stores float freely).
//   Phase order: own-half MACs (LDS h) first -> partner store latency hides.
// ---------------------------------------------------------------------------
__global__ __attribute__((amdgpu_flat_work_group_size(512, 512)))
__attribute__((amdgpu_waves_per_eu(2, 2)))
void k_rec9(const float* __restrict__ W2,
            const float* __restrict__ b2,
            float* __restrict__ out,
            float* __restrict__ hlast,
            unsigned* __restrict__ hxc) {
    const int wgid = blockIdx.x;
    const int b = wgid & 63;
    const int half = wgid >> 6;
    const int t = threadIdx.x;
    const int lane = t & 63;
    const int wv = t >> 6;
    const int colbase = half << 8;

    __shared__ float part[8][256];                 // 8 KB
    __shared__ __align__(4) _Float16 hsmem[256];   // own half of h
    const unsigned* hs32 = (const unsigned*)hsmem;

    // one-time: pack W2 slice into 128 h2 registers.
    h2 wreg[4][32];
    {
        const int pown = (half << 7) + (wv << 4);        // own global pair base
        const int popp = ((1 - half) << 7) + (wv << 4);  // partner pair base
#pragma unroll
        for (int ci = 0; ci < 4; ci++) {
            const float2* wrow =
                (const float2*)(W2 + (size_t)(colbase + lane + (ci << 6)) * HH);
#pragma unroll
            for (int g = 0; g < 16; g++) {
                float2 f = wrow[pown + g];
                wreg[ci][g] = pk(f.x, f.y);
            }
#pragma unroll
            for (int g = 0; g < 16; g++) {
                float2 f = wrow[popp + g];
                wreg[ci][16 + g] = pk(f.x, f.y);
            }
        }
    }
    if (t < 256) hsmem[t] = (_Float16)0.0f;
    float bias = 0.f;
    if (t < 256) bias = b2[colbase + t];
    float* po = out + (size_t)b * HH + colbase + t;      // deref only t<256
    const unsigned* rd = hxc + (size_t)b * 256 + ((1 - half) << 7) +
                         (wv << 4) + (lane & 15);        // slot s-1 read
    unsigned* wr = hxc + (size_t)b * 256 + (half << 7) + (t >> 1);
    float hn = 0.0f;
    __syncthreads();

    for (int s = 0; s < SS; ++s) {
        float xpv = 0.f;
        if (t < 256) xpv = *po;            // early; hidden under MACs

        // ---- phase 1: own-half pairs from LDS ----
        unsigned hv1 = hs32[(wv << 4) + (lane & 15)];
        h2 aA[4], aB[4];
#pragma unroll
        for (int ci = 0; ci < 4; ci++) { aA[ci] = h2{0, 0}; aB[ci] = h2{0, 0}; }
#pragma unroll
        for (int g = 0; g < 16; g++) {
            h2 hp = bc_h2((unsigned)__builtin_amdgcn_readlane((int)hv1, g));
            if (g & 1) {
                aB[0] += wreg[0][g] * hp; aB[1] += wreg[1][g] * hp;
                aB[2] += wreg[2][g] * hp; aB[3] += wreg[3][g] * hp;
            } else {
                aA[0] += wreg[0][g] * hp; aA[1] += wreg[1][g] * hp;
                aA[2] += wreg[2][g] * hp; aA[3] += wreg[3][g] * hp;
            }
        }

        // ---- partner-half pairs: poll slot s-1 (datum is the sync) ----
        unsigned hv2 = 0;
        if (s > 0) {
            const unsigned* p = rd + (size_t)(s - 1) * (BB * 256);
            do {
                hv2 = __hip_atomic_load(p, __ATOMIC_RELAXED,
                                        __HIP_MEMORY_SCOPE_AGENT);
            } while (hv2 == 0xFFFFFFFFu);
        }
#pragma unroll
        for (int g = 0; g < 16; g++) {
            h2 hp = bc_h2((unsigned)__builtin_amdgcn_readlane((int)hv2, g));
            if (g & 1) {
                aB[0] += wreg[0][16 + g] * hp; aB[1] += wreg[1][16 + g] * hp;
                aB[2] += wreg[2][16 + g] * hp; aB[3] += wreg[3][16 + g] * hp;
            } else {
                aA[0] += wreg[0][16 + g] * hp; aA[1] += wreg[1][16 + g] * hp;
                aA[2] += wreg[2][16 + g] * hp; aA[3] += wreg[3][16 + g] * hp;
            }
        }
#pragma unroll
        for (int ci = 0; ci < 4; ci++) {
            h2 sv = aA[ci] + aB[ci];
            part[wv][lane + (ci << 6)] = (float)sv.x + (float)sv.y;
        }
        bar_lds();  // A: partials visible; hsmem reads drained

        if (t < 256) {
            float z = part[0][t] + part[1][t] + part[2][t] + part[3][t] +
                      part[4][t] + part[5][t] + part[6][t] + part[7][t] +
                      bias + xpv;
            hn = fast_tanh(z);
            *po = hn;
            hsmem[t] = (_Float16)hn;
            float ho = __shfl_xor(hn, 1);
            if (!(t & 1)) {
                __hip_atomic_store(wr + (size_t)s * (BB * 256),
                                   bc_u(pk(hn, ho)),
                                   __ATOMIC_RELAXED, __HIP_MEMORY_SCOPE_AGENT);
            }
        }
        po += BB * HH;
        bar_lds();  // B: new hsmem visible; part reusable
    }
    if (t < 256) hlast[(size_t)b * HH + colbase + t] = hn;
}

// ---------------------------------------------------------------------------
// Fallback single-CU recurrence (round-9 k_rec8, 856us) if ws too small.
// ---------------------------------------------------------------------------
__global__ __attribute__((amdgpu_flat_work_group_size(512, 512)))
__attribute__((amdgpu_waves_per_eu(2, 2)))
void k_rec8(const float* __restrict__ W2,
            const float* __restrict__ b2,
            float* __restrict__ out,
            float* __restrict__ hlast) {
    const int b = blockIdx.x;
    const int t = threadIdx.x;
    const int lane = t & 63;
    const int w = t >> 6;

    __shared__ uint4 wlds[16][512];
    __shared__ float part[8][512];
    __shared__ __align__(4) _Float16 hsmem[HH];
    const unsigned* hs32 = (const unsigned*)hsmem;

    h2 wreg[6][32];
#pragma unroll
    for (int ci = 0; ci < 6; ci++) {
        const float2* src =
            (const float2*)(W2 + (size_t)(lane + 64 * ci) * HH) + (w << 5);
#pragma unroll
        for (int g = 0; g < 32; g++) wreg[ci][g] = pk(src[g].x, src[g].y);
    }
#pragma unroll
    for (int cc = 0; cc < 2; cc++) {
        const float2* src =
            (const float2*)(W2 + (size_t)(lane + 384 + 64 * cc) * HH) + (w << 5);
#pragma unroll
        for (int q = 0; q < 8; q++) {
            uint4 u;
            u.x = bc_u(pk(src[4 * q + 0].x, src[4 * q + 0].y));
            u.y = bc_u(pk(src[4 * q + 1].x, src[4 * q + 1].y));
            u.z = bc_u(pk(src[4 * q + 2].x, src[4 * q + 2].y));
            u.w = bc_u(pk(src[4 * q + 3].x, src[4 * q + 3].y));
            wlds[cc * 8 + q][t] = u;
        }
    }
    hsmem[t] = (_Float16)0.0f;
    const float bias = b2[t];
    float* po = out + (size_t)b * HH + t;
    float hn = 0.0f;
    __syncthreads();

    for (int step = 0; step < SS; ++step) {
        float xpv = *po;
        unsigned hv = hs32[(w << 5) + (lane & 31)];

        h2 accA[8], accB[8];
#pragma unroll
        for (int c = 0; c < 8; c++) { accA[c] = h2{0, 0}; accB[c] = h2{0, 0}; }
#pragma unroll
        for (int q = 0; q < 8; q++) {
            uint4 u6 = wlds[q][t];
            uint4 u7 = wlds[8 + q][t];
            unsigned w6[4] = {u6.x, u6.y, u6.z, u6.w};
            unsigned w7[4] = {u7.x, u7.y, u7.z, u7.w};
#pragma unroll
            for (int gg = 0; gg < 4; gg++) {
                const int g = 4 * q + gg;
                h2 hp = bc_h2((unsigned)__builtin_amdgcn_readlane((int)hv, g));
                if (gg & 1) {
                    accB[0] += wreg[0][g] * hp; accB[1] += wreg[1][g] * hp;
                    accB[2] += wreg[2][g] * hp; accB[3] += wreg[3][g] * hp;
                    accB[4] += wreg[4][g] * hp; accB[5] += wreg[5][g] * hp;
                    accB[6] += bc_h2(w6[gg]) * hp;
                    accB[7] += bc_h2(w7[gg]) * hp;
                } else {
                    accA[0] += wreg[0][g] * hp; accA[1] += wreg[1][g] * hp;
                    accA[2] += wreg[2][g] * hp; accA[3] += wreg[3][g] * hp;
                    accA[4] += wreg[4][g] * hp; accA[5] += wreg[5][g] * hp;
                    accA[6] += bc_h2(w6[gg]) * hp;
                    accA[7] += bc_h2(w7[gg]) * hp;
                }
            }
        }
#pragma unroll
        for (int c = 0; c < 8; c++) {
            h2 s = accA[c] + accB[c];
            part[w][lane + 64 * c] = (float)s.x + (float)s.y;
        }
        bar_lds();

        float z = part[0][t] + part[1][t] + part[2][t] + part[3][t] +
                  part[4][t] + part[5][t] + part[6][t] + part[7][t] +
                  bias + xpv;
        hn = fast_tanh(z);
        hsmem[t] = (_Float16)hn;
        *po = hn;
        po += BB * HH;
        bar_lds();
    }
    hlast[(size_t)b * HH + t] = hn;
}

extern "C" void kernel_launch(void* const* d_in, const int* in_sizes, int n_in,
                              void* d_out, int out_size, void* d_ws, size_t ws_size,
                              hipStream_t stream) {
    const float* x  = (const float*)d_in[0];
    const float* W1 = (const float*)d_in[1];
    const float* b1 = (const float*)d_in[2];
    const float* W2 = (const float*)d_in[3];
    const float* b2 = (const float*)d_in[4];
    float* out = (float*)d_out;

    k_ingemm2<<<dim3(MM / 128, HH / 128), 256, 0, stream>>>(x, W1, b1, out);
    if (ws_size >= HXC_BYTES) {
        unsigned* hxc = (unsigned*)d_ws;
        hipMemsetAsync(d_ws, 0xFF, HXC_BYTES, stream);   // sentinel-fill
        k_rec9<<<128, 512, 0, stream>>>(W2, b2, out,
                                        out + (size_t)SS * BB * HH, hxc);
    } else {
        k_rec8<<<BB, 512, 0, stream>>>(W2, b2, out, out + (size_t)SS * BB * HH);
    }
}